// Round 5
// baseline (469.131 us; speedup 1.0000x reference)
//
#include <hip/hip_runtime.h>
#include <hip/hip_bf16.h>
#include <stdint.h>

#define TOK   16384
#define DIM   256
#define HIDN  1024
#define OUTD  256
#define NEXP  8
#define NSH   3
#define NSLOT 11
#define TM    64
#define CH    256

typedef short bf16x8  __attribute__((ext_vector_type(8)));
typedef float f32x4   __attribute__((ext_vector_type(4)));
typedef short short4v __attribute__((ext_vector_type(4)));

// ---- workspace layout (bytes) ----
constexpr size_t XB_OFF   = 0;                                        // T*D bf16
constexpr size_t W1P_OFF  = XB_OFF  + (size_t)TOK*DIM*2;
constexpr size_t W2P_OFF  = W1P_OFF + (size_t)NSLOT*DIM*HIDN*2;
constexpr size_t WTS_OFF  = W2P_OFF + (size_t)NSLOT*HIDN*OUTD*2;
constexpr size_t IDS_OFF  = WTS_OFF + (size_t)TOK*2*4;
constexpr size_t CNT_OFF  = IDS_OFF + (size_t)TOK*2*4;
constexpr size_t LTOK_OFF = CNT_OFF + 256;
constexpr size_t LW_OFF   = LTOK_OFF + (size_t)NEXP*TOK*4;
constexpr size_t WS_NEED  = LW_OFF + (size_t)NEXP*TOK*4;

__device__ __forceinline__ unsigned short f2bf(float f) {
    __hip_bfloat16 h = __float2bfloat16(f);
    return *reinterpret_cast<unsigned short*>(&h);
}

__device__ __forceinline__ f32x4 mfma16(bf16x8 a, bf16x8 b, f32x4 c) {
    return __builtin_amdgcn_mfma_f32_16x16x32_bf16(a, b, c, 0, 0, 0);
}

// async global->LDS, 16B per lane. LDS dest = uniform base + lane*16.
__device__ __forceinline__ void gload_lds16(const void* g, void* l) {
    __builtin_amdgcn_global_load_lds(
        (const __attribute__((address_space(1))) unsigned int*)g,
        (__attribute__((address_space(3))) unsigned int*)l, 16, 0, 0);
}

// stage one 16KB packed-W slice with 8 waves (2 x 1KB per wave)
__device__ __forceinline__ void stage16k(const char* src, char* dst, int w, int lane) {
    gload_lds16(src + w*1024 + lane*16,        dst + w*1024);
    gload_lds16(src + 8192 + w*1024 + lane*16, dst + 8192 + w*1024);
}

// XOR swizzle for 64x256 bf16 H tile (row stride 512B)
__device__ __forceinline__ int swz(int row, int colb) {
    return ((row << 9) + colb) ^ ((row & 7) << 4);
}

// ---- fp32 -> bf16 of X ----
__global__ void k_convert_x(const float* __restrict__ x, short* __restrict__ xb) {
    int i = blockIdx.x * 256 + threadIdx.x;
    float4 v = reinterpret_cast<const float4*>(x)[i];
    short4v o;
    o[0] = (short)f2bf(v.x); o[1] = (short)f2bf(v.y);
    o[2] = (short)f2bf(v.z); o[3] = (short)f2bf(v.w);
    reinterpret_cast<short4v*>(xb)[i] = o;
}

// ---- fp32 weights -> bf16 packed B-frag order, via LDS transpose ----
// packed elem offset = (((slot*KT + kt)*NT + nt)*64 + lane)*8 + j ;
// n = nt*16 + (lane&15), k = kt*32 + 8*(lane>>4) + j.
// Block: one (slot, kt, group-of-4-nt) -> 32k x 64n fp32 tile.
__global__ __launch_bounds__(256) void k_convert_w(
    const float* __restrict__ sw1, const float* __restrict__ iw1,
    const float* __restrict__ sw2, const float* __restrict__ iw2,
    short* __restrict__ w1p, short* __restrict__ w2p) {
    __shared__ float tile[32][68];
    int bid = blockIdx.x, tid = threadIdx.x;
    const int W1B = NSLOT * 8 * 16;            // 1408
    bool isW1 = bid < W1B;
    int b = isW1 ? bid : bid - W1B;
    int NTG = isW1 ? 16 : 4;
    int KT  = isW1 ? 8 : 32;
    int NT  = isW1 ? 64 : 16;
    int Nd  = isW1 ? HIDN : OUTD;
    int ntg = b % NTG; b /= NTG;
    int kt  = b % KT;
    int slot = b / KT;
    const float* src;
    if (isW1) src = (slot < NSH) ? sw1 + (size_t)slot*DIM*HIDN  : iw1 + (size_t)(slot-NSH)*DIM*HIDN;
    else      src = (slot < NSH) ? sw2 + (size_t)slot*HIDN*OUTD : iw2 + (size_t)(slot-NSH)*HIDN*OUTD;
    // coalesced load of 32x64 fp32 tile
    {
        int tr = tid >> 3, tc = (tid & 7) * 8;
        const float* s = src + (size_t)(kt*32 + tr)*Nd + ntg*64 + tc;
        float4 v0 = *reinterpret_cast<const float4*>(s);
        float4 v1 = *reinterpret_cast<const float4*>(s + 4);
        *reinterpret_cast<float4*>(&tile[tr][tc])     = v0;
        *reinterpret_cast<float4*>(&tile[tr][tc + 4]) = v1;
    }
    __syncthreads();
    // packed write: one 8-elem fragment per thread, coalesced 16B stores
    {
        int ntl = tid >> 6, lane = tid & 63;
        int n  = ntl*16 + (lane & 15);
        int k8 = (lane >> 4) * 8;
        bf16x8 o;
        #pragma unroll
        for (int j = 0; j < 8; ++j) o[j] = (short)f2bf(tile[k8 + j][n]);
        size_t gidx = (((size_t)slot*KT + kt)*NT + ntg*4 + ntl)*64 + lane;
        short* dst = isW1 ? w1p : w2p;
        reinterpret_cast<bf16x8*>(dst)[gidx] = o;
    }
}

// ---- gating: fp32-exact logits, top-2, renormalized, pre-scaled by 0.5 ----
__global__ void k_gate(const float* __restrict__ x, const float* __restrict__ gw,
                       const float* __restrict__ gb, float* __restrict__ wts,
                       int* __restrict__ ids) {
    int wid = threadIdx.x >> 6, lane = threadIdx.x & 63;
    int t = blockIdx.x * 4 + wid;
    const float* xr = x + (size_t)t * DIM;
    float acc[NEXP] = {0.f,0.f,0.f,0.f,0.f,0.f,0.f,0.f};
    #pragma unroll
    for (int i = 0; i < DIM/64; ++i) {
        int d = i*64 + lane;
        float xv = xr[d];
        const float* g = gw + (size_t)d * NEXP;
        #pragma unroll
        for (int e = 0; e < NEXP; ++e) acc[e] = fmaf(xv, g[e], acc[e]);
    }
    #pragma unroll
    for (int off = 32; off; off >>= 1) {
        #pragma unroll
        for (int e = 0; e < NEXP; ++e) acc[e] += __shfl_xor(acc[e], off, 64);
    }
    if (lane == 0) {
        float l[NEXP];
        #pragma unroll
        for (int e = 0; e < NEXP; ++e) l[e] = acc[e] + gb[e];
        int e0 = 0; float v0 = l[0];
        #pragma unroll
        for (int e = 1; e < NEXP; ++e) if (l[e] > v0) { v0 = l[e]; e0 = e; }
        int e1 = -1; float v1 = -1e30f;
        #pragma unroll
        for (int e = 0; e < NEXP; ++e) if (e != e0 && l[e] > v1) { v1 = l[e]; e1 = e; }
        float r = expf(v1 - v0);
        float w0 = 0.5f / (1.f + r);
        float w1 = 0.5f * r / (1.f + r);
        ids[2*t]   = e0;  ids[2*t+1] = e1;
        wts[2*t]   = w0;  wts[2*t+1] = w1;
    }
}

// ---- build per-expert token lists ----
__global__ void k_route(const int* __restrict__ ids, const float* __restrict__ wts,
                        int* __restrict__ cnt, int* __restrict__ ltok,
                        float* __restrict__ lw) {
    int t = blockIdx.x * 256 + threadIdx.x;
    #pragma unroll
    for (int k = 0; k < 2; ++k) {
        int e = ids[2*t + k];
        int p = atomicAdd(&cnt[e], 1);
        ltok[(size_t)e*TOK + p] = t;
        lw  [(size_t)e*TOK + p] = wts[2*t + k];
    }
}

// ---- mega-kernel: one (token-tile, hidden-chunk, slot) per block ----
// W staged async to LDS (global_load_lds, dbuf, m97 2-barrier); A in regs
// with 1-deep prefetch; H in swizzled LDS between phases; split-K atomics.
__global__ __launch_bounds__(512, 4) void k_moe(
    const short* __restrict__ xb, const short* __restrict__ w1p, const short* __restrict__ w2p,
    const float* __restrict__ sb1, const float* __restrict__ sb2,
    const float* __restrict__ ib1, const float* __restrict__ ib2,
    const float* __restrict__ obj, const int* __restrict__ cnt,
    const int* __restrict__ ltok, const float* __restrict__ lw,
    float* __restrict__ out)
{
    __shared__ __align__(16) char Hs[32768];       // 64 x 256 bf16, swizzled
    __shared__ __align__(16) char Wb[2][16384];    // W staging dbuf
    __shared__ int   tokl[TM];
    __shared__ float twl[TM];

    const int slot = blockIdx.z;
    const int c    = blockIdx.y;
    const int m0   = blockIdx.x * TM;
    const bool sh  = slot < NSH;
    const int e    = slot - NSH;
    int count = TOK;
    if (!sh) { count = cnt[e]; if (m0 >= count) return; }

    const int tid  = threadIdx.x;
    const int w    = tid >> 6, lane = tid & 63;
    const int wm   = w >> 2,   wn   = w & 3;
    const int lrow = lane & 15, g   = lane >> 4;

    if (tid < TM) {
        if (sh) {
            tokl[tid] = m0 + tid;
            twl[tid]  = 0.5f * obj[(size_t)(m0 + tid)*NSH + slot];
        } else {
            int p = m0 + tid;
            bool ok = p < count;
            tokl[tid] = ok ? ltok[(size_t)e*TOK + p] : 0;
            twl[tid]  = ok ? lw[(size_t)e*TOK + p] : 0.f;   // already 0.5-scaled
        }
    }
    __syncthreads();

    const char* w1base = (const char*)w1p;
    const char* w2base = (const char*)w2p;
    // packed W1 slice (slot, kt, nt in [c*16, c*16+16)) : contiguous 16KB
    #define W1SLICE(kt) (w1base + ((((size_t)slot*8 + (kt))*64 + c*16) << 10))
    // packed W2 slice (slot, kt2 = c*8+kt, nt 0..15) : contiguous 16KB
    #define W2SLICE(kt) (w2base + ((((size_t)slot*32 + c*8 + (kt))*16) << 10))

    int tA[2];
    #pragma unroll
    for (int m = 0; m < 2; ++m) tA[m] = tokl[wm*32 + m*16 + lrow];

    // ---- phase 1: acc1 = X(64x256) @ W1 chunk (wave: 32 rows x 64 cols) ----
    f32x4 acc1[2][4] = {};
    bf16x8 aC[2], aN[2];
    #pragma unroll
    for (int m = 0; m < 2; ++m)
        aC[m] = *reinterpret_cast<const bf16x8*>(xb + (size_t)tA[m]*DIM + g*8);
    stage16k(W1SLICE(0), Wb[0], w, lane);
    __syncthreads();
    for (int kt = 0; kt < 8; ++kt) {
        if (kt < 7) {
            stage16k(W1SLICE(kt+1), Wb[(kt+1)&1], w, lane);
            #pragma unroll
            for (int m = 0; m < 2; ++m)
                aN[m] = *reinterpret_cast<const bf16x8*>(
                    xb + (size_t)tA[m]*DIM + (kt+1)*32 + g*8);
        }
        const char* buf = Wb[kt&1];
        bf16x8 bfr[4];
        #pragma unroll
        for (int n = 0; n < 4; ++n)
            bfr[n] = *reinterpret_cast<const bf16x8*>(buf + ((wn*4 + n)*64 + lane)*16);
        #pragma unroll
        for (int m = 0; m < 2; ++m)
            #pragma unroll
            for (int n = 0; n < 4; ++n)
                acc1[m][n] = mfma16(aC[m], bfr[n], acc1[m][n]);
        aC[0] = aN[0]; aC[1] = aN[1];
        __syncthreads();
    }

    // overlap: issue W2 kt=0 staging before H-write (drained by next barrier)
    stage16k(W2SLICE(0), Wb[0], w, lane);

    // H = relu(acc1 + b1) * tw -> LDS bf16 (swizzled)
    {
        const float* b1 = sh ? (sb1 + slot*HIDN) : (ib1 + (size_t)e*HIDN);
        #pragma unroll
        for (int n = 0; n < 4; ++n) {
            int colc = wn*64 + n*16 + lrow;
            float bias = b1[c*CH + colc];
            #pragma unroll
            for (int m = 0; m < 2; ++m)
                #pragma unroll
                for (int r = 0; r < 4; ++r) {
                    int row = wm*32 + m*16 + g*4 + r;
                    float v = fmaxf(acc1[m][n][r] + bias, 0.f) * twl[row];
                    *reinterpret_cast<unsigned short*>(Hs + swz(row, colc*2)) = f2bf(v);
                }
        }
    }
    __syncthreads();

    // ---- phase 2: acc2 = H(64x256) @ W2 chunk (out cols 0..255) ----
    f32x4 acc2[2][4] = {};
    for (int kt = 0; kt < 8; ++kt) {
        if (kt < 7) stage16k(W2SLICE(kt+1), Wb[(kt+1)&1], w, lane);
        const char* buf = Wb[kt&1];
        bf16x8 a2[2], bfr[4];
        #pragma unroll
        for (int m = 0; m < 2; ++m)
            a2[m] = *reinterpret_cast<const bf16x8*>(
                Hs + swz(wm*32 + m*16 + lrow, kt*64 + g*16));
        #pragma unroll
        for (int n = 0; n < 4; ++n)
            bfr[n] = *reinterpret_cast<const bf16x8*>(buf + ((wn*4 + n)*64 + lane)*16);
        #pragma unroll
        for (int m = 0; m < 2; ++m)
            #pragma unroll
            for (int n = 0; n < 4; ++n)
                acc2[m][n] = mfma16(a2[m], bfr[n], acc2[m][n]);
        __syncthreads();
    }

    // epilogue: atomic split-K accumulate (+ tw*b2 once, from c==0)
    {
        const float* b2 = sh ? (sb2 + slot*OUTD) : (ib2 + (size_t)e*OUTD);
        #pragma unroll
        for (int m = 0; m < 2; ++m)
            #pragma unroll
            for (int n = 0; n < 4; ++n) {
                int col = wn*64 + n*16 + lrow;
                #pragma unroll
                for (int r = 0; r < 4; ++r) {
                    int row = wm*32 + m*16 + g*4 + r;
                    if (sh || (m0 + row < count)) {
                        int t = tokl[row];
                        float v = acc2[m][n][r];
                        if (c == 0) v += twl[row] * b2[col];
                        atomicAdd(&out[(size_t)t*OUTD + col], v);
                    }
                }
            }
    }
    #undef W1SLICE
    #undef W2SLICE
}

extern "C" void kernel_launch(void* const* d_in, const int* in_sizes, int n_in,
                              void* d_out, int out_size, void* d_ws, size_t ws_size,
                              hipStream_t stream) {
    const float* x   = (const float*)d_in[0];
    const float* obj = (const float*)d_in[1];
    const float* gw  = (const float*)d_in[2];
    const float* gb  = (const float*)d_in[3];
    const float* sw1 = (const float*)d_in[4];
    const float* sb1 = (const float*)d_in[5];
    const float* sw2 = (const float*)d_in[6];
    const float* sb2 = (const float*)d_in[7];
    const float* iw1 = (const float*)d_in[8];
    const float* ib1 = (const float*)d_in[9];
    const float* iw2 = (const float*)d_in[10];
    const float* ib2 = (const float*)d_in[11];
    float* out = (float*)d_out;
    char* ws = (char*)d_ws;
    if (ws_size < WS_NEED) return;

    short* xb   = (short*)(ws + XB_OFF);
    short* w1p  = (short*)(ws + W1P_OFF);
    short* w2p  = (short*)(ws + W2P_OFF);
    float* wts  = (float*)(ws + WTS_OFF);
    int*   ids  = (int*)  (ws + IDS_OFF);
    int*   cnt  = (int*)  (ws + CNT_OFF);
    int*   ltok = (int*)  (ws + LTOK_OFF);
    float* lwt  = (float*)(ws + LW_OFF);

    hipMemsetAsync(ws + CNT_OFF, 0, 256, stream);
    hipMemsetAsync(out, 0, (size_t)out_size * 4, stream);
    k_convert_x<<<(TOK*DIM/4)/256, 256, 0, stream>>>(x, xb);
    k_convert_w<<<NSLOT*8*16 + NSLOT*32*4, 256, 0, stream>>>(sw1, iw1, sw2, iw2, w1p, w2p);
    k_gate<<<TOK/4, 256, 0, stream>>>(x, gw, gb, wts, ids);
    k_route<<<TOK/256, 256, 0, stream>>>(ids, wts, cnt, ltok, lwt);
    k_moe<<<dim3(TOK/TM, HIDN/CH, NSLOT), 512, 0, stream>>>(
        xb, w1p, w2p, sb1, sb2, ib1, ib2, obj, cnt, ltok, lwt, out);
}